// Round 5
// baseline (292.710 us; speedup 1.0000x reference)
//
#include <hip/hip_runtime.h>

typedef float  f32x4  __attribute__((ext_vector_type(4)));
typedef __bf16 bf16x8 __attribute__((ext_vector_type(8)));

#define CC 384

__device__ __forceinline__ unsigned short f2bf(float f) {
  union { float f; unsigned int u; } x; x.f = f;
  unsigned int u = x.u;
  return (unsigned short)((u + 0x7fffu + ((u >> 16) & 1u)) >> 16);
}

__device__ __forceinline__ f32x4 mfma16(bf16x8 a, bf16x8 b, f32x4 c) {
  return __builtin_amdgcn_mfma_f32_16x16x32_bf16(a, b, c, 0, 0, 0);
}

// ---------------- kernel 0: repack W into B-fragment layout ----------------
// dst: [kk(0..11)][nt(0..11)][lane(0..63)][j(0..7)] bf16
// element (k, n): kk=k>>5, lane=((k>>3)&3)*16 + (n&15), j=k&7, nt=n>>4
__global__ void repack_w(const float* __restrict__ Wq, const float* __restrict__ Wk,
                         const float* __restrict__ Wv, unsigned short* __restrict__ wf) {
  int e = blockIdx.x * 512 + threadIdx.x;      // 73728 total, exact
  int k = e / 192;
  int n = e - k * 192;
  const float* W = (n < 64) ? Wq : (n < 128) ? Wk : Wv;
  float val = W[k * 64 + (n & 63)];
  int kk = k >> 5;
  int lane = (((k >> 3) & 3) << 4) | (n & 15);
  int j = k & 7;
  int nt = n >> 4;
  wf[(size_t)(((kk * 12 + nt) << 6) + lane) * 8 + j] = f2bf(val);
}

// ---------------- fused kernel: projection + column-softmax attention ----------------
// one block per batch, 8 waves; wave w owns m-tiles {w, 15-w}. LDS 48KB -> 2 blocks/CU.
__global__ __launch_bounds__(512, 4) void fused(const float* __restrict__ x,
                                                const unsigned short* __restrict__ wf,
                                                unsigned short* __restrict__ kg,
                                                unsigned short* __restrict__ vg,
                                                float* __restrict__ out) {
  // LDS (49,152 B): Sx[256][72] bf16 (W-stage dbuf overlay / q-scratch / exp-weights),
  //                 pm/ps/gg [16][64] f32
  __shared__ __attribute__((aligned(16))) unsigned char smem[49152];
  unsigned short (*Sx)[72] = (unsigned short(*)[72])smem;
  float* pm = (float*)(smem + 36864);
  float* ps = pm + 1024;
  float* gg = ps + 1024;
  unsigned short* wst = (unsigned short*)smem;   // W stage: 2 x 6144 shorts (overlays Sx)

  const int tid = threadIdx.x;
  const int w = tid >> 6, lane = tid & 63;
  const int l15 = lane & 15, lhi = lane >> 4;
  const int b = blockIdx.x;
  const int mts[2] = {w, 15 - w};

  // ================= projection (R3 structure: LDS-dbuf W, reg-prefetch x) =================
  const float* xr0 = x + ((size_t)b * 256 + mts[0] * 16 + l15) * CC + lhi * 8;
  const float* xr1 = x + ((size_t)b * 256 + mts[1] * 16 + l15) * CC + lhi * 8;

  f32x4 zero = {0.f, 0.f, 0.f, 0.f};
  f32x4 acc[2][12];
#pragma unroll
  for (int i = 0; i < 2; ++i)
#pragma unroll
    for (int nt = 0; nt < 12; ++nt) acc[i][nt] = zero;

#define STAGE(kp_, b_) do {                                                                           \
    const unsigned short* s_ = wf + (size_t)(kp_) * 6144 + tid * 8;                                   \
    unsigned short* d_ = wst + (b_) * 6144 + tid * 8;                                                 \
    __builtin_amdgcn_global_load_lds((const __attribute__((address_space(1))) void*)(s_),             \
                                     (__attribute__((address_space(3))) void*)(d_), 16, 0, 0);        \
    if (tid < 256)                                                                                    \
      __builtin_amdgcn_global_load_lds((const __attribute__((address_space(1))) void*)(s_ + 4096),    \
                                       (__attribute__((address_space(3))) void*)(d_ + 4096), 16, 0, 0);\
  } while (0)

  STAGE(0, 0);
  f32x4 aC[2][2];
  aC[0][0] = *(const f32x4*)(xr0);     aC[0][1] = *(const f32x4*)(xr0 + 4);
  aC[1][0] = *(const f32x4*)(xr1);     aC[1][1] = *(const f32x4*)(xr1 + 4);

  for (int kp = 0; kp < 12; ++kp) {
    __syncthreads();  // buf[kp&1] staged; prev buf readers done
    f32x4 aN[2][2];
#pragma unroll
    for (int i = 0; i < 2; ++i) { aN[i][0] = zero; aN[i][1] = zero; }
    if (kp < 11) {
      const int o = (kp + 1) * 32;
      aN[0][0] = *(const f32x4*)(xr0 + o);     aN[0][1] = *(const f32x4*)(xr0 + o + 4);
      aN[1][0] = *(const f32x4*)(xr1 + o);     aN[1][1] = *(const f32x4*)(xr1 + o + 4);
      STAGE(kp + 1, (kp + 1) & 1);
    }
    const bf16x8* bp = (const bf16x8*)(wst + (kp & 1) * 6144) + lane;
#pragma unroll
    for (int i = 0; i < 2; ++i) {
      bf16x8 af;
#pragma unroll
      for (int j = 0; j < 4; ++j) { af[j] = (__bf16)aC[i][0][j]; af[4 + j] = (__bf16)aC[i][1][j]; }
#pragma unroll
      for (int nt = 0; nt < 12; ++nt) acc[i][nt] = mfma16(af, bp[nt * 64], acc[i][nt]);
    }
#pragma unroll
    for (int i = 0; i < 2; ++i) { aC[i][0] = aN[i][0]; aC[i][1] = aN[i][1]; }
  }
#undef STAGE
  __syncthreads();  // all W-stage reads done; Sx region free for q-scratch

  // epilogue: q (scaled) -> Sx LDS, k -> kg global [b][t][h], v -> vg global [b][h][t]
  const float qs = 0.05103103630798288f;  // 384^-0.5
#pragma unroll
  for (int i = 0; i < 2; ++i) {
    const int rb = mts[i] * 16 + lhi * 4;
#pragma unroll
    for (int nt = 0; nt < 4; ++nt) {
      const int h = nt * 16 + l15;
#pragma unroll
      for (int r = 0; r < 4; ++r) Sx[rb + r][h] = f2bf(acc[i][nt][r] * qs);
    }
#pragma unroll
    for (int nt = 4; nt < 8; ++nt) {
      const int h = (nt - 4) * 16 + l15;
#pragma unroll
      for (int r = 0; r < 4; ++r)
        kg[((size_t)b * 256 + rb + r) * 64 + h] = f2bf(acc[i][nt][r]);
    }
#pragma unroll
    for (int nt = 8; nt < 12; ++nt) {
      const int h = (nt - 8) * 16 + l15;
      unsigned long long pk =
          (unsigned long long)f2bf(acc[i][nt][0]) |
          ((unsigned long long)f2bf(acc[i][nt][1]) << 16) |
          ((unsigned long long)f2bf(acc[i][nt][2]) << 32) |
          ((unsigned long long)f2bf(acc[i][nt][3]) << 48);
      *(unsigned long long*)(vg + ((size_t)b * 64 + h) * 256 + rb) = pk;
    }
  }
  __syncthreads();  // drains LDS q writes + global k/v writes (vmcnt0+lgkmcnt0 @ barrier)

  bf16x8 qf[2][2];
#pragma unroll
  for (int i = 0; i < 2; ++i)
#pragma unroll
    for (int kk = 0; kk < 2; ++kk)
      qf[i][kk] = *(const bf16x8*)&Sx[mts[i] * 16 + l15][kk * 32 + lhi * 8];

  // ================= attention =================
  f32x4 oacc[2][4];
#pragma unroll
  for (int i = 0; i < 2; ++i)
#pragma unroll
    for (int nh = 0; nh < 4; ++nh) oacc[i][nh] = zero;

  const size_t kbase = (size_t)b * 256 * 64;
  const size_t vbase = (size_t)b * 64 * 256;

  for (int p = 0; p < 4; ++p) {
    const int p4 = 4 * p;
    const bool any = (mts[1] >= p4);
    // ---- S compute + in-register tile-column stats + exp write ----
    if (any) {
      bf16x8 kf[4][2];
#pragma unroll
      for (int c = 0; c < 4; ++c)
#pragma unroll
        for (int kk = 0; kk < 2; ++kk)
          kf[c][kk] = *(const bf16x8*)(kg + kbase + (size_t)(p * 64 + c * 16 + l15) * 64 + kk * 32 + lhi * 8);
#pragma unroll
      for (int i = 0; i < 2; ++i) {
        const int mt = mts[i];
        if (mt < p4) continue;
        const int cmax = mt - p4;
        const int rowb = mt * 16 + lhi * 4;
#pragma unroll
        for (int c = 0; c < 4; ++c) {
          const int cs = c * 16 + l15;
          if (c <= cmax) {
            f32x4 s = zero;
            s = mfma16(qf[i][0], kf[c][0], s);
            s = mfma16(qf[i][1], kf[c][1], s);
            const int cg = p * 64 + cs;
            const bool v0 = (rowb + 0) >= cg, v1 = (rowb + 1) >= cg;
            const bool v2 = (rowb + 2) >= cg, v3 = (rowb + 3) >= cg;
            float m = -1e30f;
            m = fmaxf(m, v0 ? s[0] : -1e30f);
            m = fmaxf(m, v1 ? s[1] : -1e30f);
            m = fmaxf(m, v2 ? s[2] : -1e30f);
            m = fmaxf(m, v3 ? s[3] : -1e30f);
            m = fmaxf(m, __shfl_xor(m, 16));
            m = fmaxf(m, __shfl_xor(m, 32));
            const float e0 = v0 ? __expf(s[0] - m) : 0.f;
            const float e1 = v1 ? __expf(s[1] - m) : 0.f;
            const float e2 = v2 ? __expf(s[2] - m) : 0.f;
            const float e3 = v3 ? __expf(s[3] - m) : 0.f;
            float t = e0 + e1 + e2 + e3;
            t += __shfl_xor(t, 16);
            t += __shfl_xor(t, 32);
            Sx[rowb + 0][cs] = f2bf(e0);
            Sx[rowb + 1][cs] = f2bf(e1);
            Sx[rowb + 2][cs] = f2bf(e2);
            Sx[rowb + 3][cs] = f2bf(e3);
            if (lhi == 0) { pm[mt * 64 + cs] = m; ps[mt * 64 + cs] = t; }
          } else {
            if (lhi == 0) { pm[mt * 64 + cs] = -1e30f; ps[mt * 64 + cs] = 0.f; }
          }
        }
      }
    }
    __syncthreads();  // B1: pm/ps/Sx stripe complete
    // ---- per-column reduce (redundant across waves; each wave writes its gg rows) ----
    {
      float M = -1e30f;
      for (int mt = p4; mt < 16; ++mt) M = fmaxf(M, pm[mt * 64 + lane]);
      float L = 0.f;
      for (int mt = p4; mt < 16; ++mt) L += ps[mt * 64 + lane] * __expf(pm[mt * 64 + lane] - M);
      const float rv = 1.0f / L;
      int mtw = p4 + w;
      if (mtw < 16) gg[mtw * 64 + lane] = __expf(pm[mtw * 64 + lane] - M) * rv;
      mtw += 8;
      if (mtw < 16) gg[mtw * 64 + lane] = __expf(pm[mtw * 64 + lane] - M) * rv;
    }
    __syncthreads();  // B2: gg ready
    // ---- W = Sx * gg, PV accumulate ----
    if (any) {
      bf16x8 vf[4][2];
#pragma unroll
      for (int nh = 0; nh < 4; ++nh)
#pragma unroll
        for (int kk = 0; kk < 2; ++kk)
          vf[nh][kk] = *(const bf16x8*)(vg + vbase + (size_t)(nh * 16 + l15) * 256 + p * 64 + kk * 32 + lhi * 8);
#pragma unroll
      for (int i = 0; i < 2; ++i) {
        const int mt = mts[i];
        if (mt < p4) continue;
        const int grow = mt * 16 + l15;
        const int dmax = mt - p4;
#pragma unroll
        for (int kk = 0; kk < 2; ++kk) {
          if (kk == 1 && dmax <= 1) continue;  // upper half fully masked
          const int c0 = kk * 32 + lhi * 8;
          bf16x8 se = *(const bf16x8*)&Sx[grow][c0];
          f32x4 gA = *(const f32x4*)&gg[mt * 64 + c0];
          f32x4 gB = *(const f32x4*)&gg[mt * 64 + c0 + 4];
          const int cg0 = p * 64 + c0;
          bf16x8 wfr;
#pragma unroll
          for (int j = 0; j < 4; ++j)
            wfr[j] = (cg0 + j <= grow) ? (__bf16)((float)se[j] * gA[j]) : (__bf16)0.f;
#pragma unroll
          for (int j = 0; j < 4; ++j)
            wfr[4 + j] = (cg0 + 4 + j <= grow) ? (__bf16)((float)se[4 + j] * gB[j]) : (__bf16)0.f;
#pragma unroll
          for (int nh = 0; nh < 4; ++nh) oacc[i][nh] = mfma16(wfr, vf[nh][kk], oacc[i][nh]);
        }
      }
    }
  }
  // ---- output ----
#pragma unroll
  for (int i = 0; i < 2; ++i) {
    const int rb = mts[i] * 16 + lhi * 4;
#pragma unroll
    for (int nh = 0; nh < 4; ++nh) {
      const int h = nh * 16 + l15;
#pragma unroll
      for (int r = 0; r < 4; ++r)
        out[(size_t)b * 16384 + (size_t)(rb + r) * 64 + h] = oacc[i][nh][r];
    }
  }
}

extern "C" void kernel_launch(void* const* d_in, const int* in_sizes, int n_in,
                              void* d_out, int out_size, void* d_ws, size_t ws_size,
                              hipStream_t stream) {
  const float* x  = (const float*)d_in[0];
  const float* Wq = (const float*)d_in[1];
  const float* Wk = (const float*)d_in[2];
  const float* Wv = (const float*)d_in[3];
  float* out = (float*)d_out;

  unsigned short* kg = (unsigned short*)d_ws;              // [512][256][64] bf16
  unsigned short* vg = kg + (size_t)512 * 256 * 64;        // [512][64][256] bf16
  unsigned short* wf = vg + (size_t)512 * 256 * 64;        // 73728 bf16 frag-packed

  repack_w<<<144, 512, 0, stream>>>(Wq, Wk, Wv, wf);
  fused<<<512, 512, 0, stream>>>(x, wf, kg, vg, out);
}

// Round 6
// 102.738 us; speedup vs baseline: 2.8491x; 2.8491x over previous
//
#include <hip/hip_runtime.h>

typedef float  f32x4  __attribute__((ext_vector_type(4)));
typedef __bf16 bf16x8 __attribute__((ext_vector_type(8)));

#define CC 384

__device__ __forceinline__ unsigned short f2bf(float f) {
  union { float f; unsigned int u; } x; x.f = f;
  unsigned int u = x.u;
  return (unsigned short)((u + 0x7fffu + ((u >> 16) & 1u)) >> 16);
}

__device__ __forceinline__ f32x4 mfma16(bf16x8 a, bf16x8 b, f32x4 c) {
  return __builtin_amdgcn_mfma_f32_16x16x32_bf16(a, b, c, 0, 0, 0);
}

// ---------------- kernel 0: repack W into B-fragment layout ----------------
// dst: [kk(0..11)][nt(0..11)][lane(0..63)][j(0..7)] bf16
// element (k, n): kk=k>>5, lane=((k>>3)&3)*16 + (n&15), j=k&7, nt=n>>4
__global__ void repack_w(const float* __restrict__ Wq, const float* __restrict__ Wk,
                         const float* __restrict__ Wv, unsigned short* __restrict__ wf) {
  int e = blockIdx.x * 512 + threadIdx.x;      // 73728 total, exact
  int k = e / 192;
  int n = e - k * 192;
  const float* W = (n < 64) ? Wq : (n < 128) ? Wk : Wv;
  float val = W[k * 64 + (n & 63)];
  int kk = k >> 5;
  int lane = (((k >> 3) & 3) << 4) | (n & 15);
  int j = k & 7;
  int nt = n >> 4;
  wf[(size_t)(((kk * 12 + nt) << 6) + lane) * 8 + j] = f2bf(val);
}

// ---------------- fused kernel: projection + column-softmax attention ----------------
// one block per batch, 8 waves; wave w owns m-tiles {w, 15-w}. LDS 48KB + VGPR<=128
// -> 2 blocks/CU co-resident (the CRITICAL occupancy property; do not cap VGPRs below
// the ~116 this code needs — launch_bounds(512,4) forced 64 and spilled acc to scratch,
// 640MB of scratch traffic, 3.5x slowdown. Measured R5.)
__global__ __launch_bounds__(512, 2) void fused(const float* __restrict__ x,
                                                const unsigned short* __restrict__ wf,
                                                unsigned short* __restrict__ kg,
                                                unsigned short* __restrict__ vg,
                                                float* __restrict__ out) {
  // LDS (49,152 B): Sx[256][72] bf16 (W-stage dbuf overlay / q-scratch / exp-weights),
  //                 pm/ps/gg [16][64] f32
  __shared__ __attribute__((aligned(16))) unsigned char smem[49152];
  unsigned short (*Sx)[72] = (unsigned short(*)[72])smem;
  float* pm = (float*)(smem + 36864);
  float* ps = pm + 1024;
  float* gg = ps + 1024;
  unsigned short* wst = (unsigned short*)smem;   // W stage: 2 x 6144 shorts (overlays Sx)

  const int tid = threadIdx.x;
  const int w = tid >> 6, lane = tid & 63;
  const int l15 = lane & 15, lhi = lane >> 4;
  const int b = blockIdx.x;
  const int mts[2] = {w, 15 - w};

  // ================= projection (LDS-dbuf W via global_load_lds, reg-prefetch x) =========
  const float* xr0 = x + ((size_t)b * 256 + mts[0] * 16 + l15) * CC + lhi * 8;
  const float* xr1 = x + ((size_t)b * 256 + mts[1] * 16 + l15) * CC + lhi * 8;

  f32x4 zero = {0.f, 0.f, 0.f, 0.f};
  f32x4 acc[2][12];
#pragma unroll
  for (int i = 0; i < 2; ++i)
#pragma unroll
    for (int nt = 0; nt < 12; ++nt) acc[i][nt] = zero;

#define STAGE(kp_, b_) do {                                                                           \
    const unsigned short* s_ = wf + (size_t)(kp_) * 6144 + tid * 8;                                   \
    unsigned short* d_ = wst + (b_) * 6144 + tid * 8;                                                 \
    __builtin_amdgcn_global_load_lds((const __attribute__((address_space(1))) void*)(s_),             \
                                     (__attribute__((address_space(3))) void*)(d_), 16, 0, 0);        \
    if (tid < 256)                                                                                    \
      __builtin_amdgcn_global_load_lds((const __attribute__((address_space(1))) void*)(s_ + 4096),    \
                                       (__attribute__((address_space(3))) void*)(d_ + 4096), 16, 0, 0);\
  } while (0)

  STAGE(0, 0);
  f32x4 aC[2][2];
  aC[0][0] = *(const f32x4*)(xr0);     aC[0][1] = *(const f32x4*)(xr0 + 4);
  aC[1][0] = *(const f32x4*)(xr1);     aC[1][1] = *(const f32x4*)(xr1 + 4);

  for (int kp = 0; kp < 12; ++kp) {
    __syncthreads();  // buf[kp&1] staged; prev buf readers done
    f32x4 aN[2][2];
#pragma unroll
    for (int i = 0; i < 2; ++i) { aN[i][0] = zero; aN[i][1] = zero; }
    if (kp < 11) {
      const int o = (kp + 1) * 32;
      aN[0][0] = *(const f32x4*)(xr0 + o);     aN[0][1] = *(const f32x4*)(xr0 + o + 4);
      aN[1][0] = *(const f32x4*)(xr1 + o);     aN[1][1] = *(const f32x4*)(xr1 + o + 4);
      STAGE(kp + 1, (kp + 1) & 1);
    }
    const bf16x8* bp = (const bf16x8*)(wst + (kp & 1) * 6144) + lane;
#pragma unroll
    for (int i = 0; i < 2; ++i) {
      bf16x8 af;
#pragma unroll
      for (int j = 0; j < 4; ++j) { af[j] = (__bf16)aC[i][0][j]; af[4 + j] = (__bf16)aC[i][1][j]; }
#pragma unroll
      for (int nt = 0; nt < 12; ++nt) acc[i][nt] = mfma16(af, bp[nt * 64], acc[i][nt]);
    }
#pragma unroll
    for (int i = 0; i < 2; ++i) { aC[i][0] = aN[i][0]; aC[i][1] = aN[i][1]; }
  }
#undef STAGE
  __syncthreads();  // all W-stage reads done; Sx region free for q-scratch

  // epilogue: q (scaled) -> Sx LDS, k -> kg global [b][t][h], v -> vg global [b][h][t]
  const float qs = 0.05103103630798288f;  // 384^-0.5
#pragma unroll
  for (int i = 0; i < 2; ++i) {
    const int rb = mts[i] * 16 + lhi * 4;
#pragma unroll
    for (int nt = 0; nt < 4; ++nt) {
      const int h = nt * 16 + l15;
#pragma unroll
      for (int r = 0; r < 4; ++r) Sx[rb + r][h] = f2bf(acc[i][nt][r] * qs);
    }
#pragma unroll
    for (int nt = 4; nt < 8; ++nt) {
      const int h = (nt - 4) * 16 + l15;
#pragma unroll
      for (int r = 0; r < 4; ++r)
        kg[((size_t)b * 256 + rb + r) * 64 + h] = f2bf(acc[i][nt][r]);
    }
#pragma unroll
    for (int nt = 8; nt < 12; ++nt) {
      const int h = (nt - 8) * 16 + l15;
      unsigned long long pk =
          (unsigned long long)f2bf(acc[i][nt][0]) |
          ((unsigned long long)f2bf(acc[i][nt][1]) << 16) |
          ((unsigned long long)f2bf(acc[i][nt][2]) << 32) |
          ((unsigned long long)f2bf(acc[i][nt][3]) << 48);
      *(unsigned long long*)(vg + ((size_t)b * 64 + h) * 256 + rb) = pk;
    }
  }
  __syncthreads();  // drains LDS q writes + global k/v writes before attn reads

  bf16x8 qf[2][2];
#pragma unroll
  for (int i = 0; i < 2; ++i)
#pragma unroll
    for (int kk = 0; kk < 2; ++kk)
      qf[i][kk] = *(const bf16x8*)&Sx[mts[i] * 16 + l15][kk * 32 + lhi * 8];

  // ================= attention =================
  f32x4 oacc[2][4];
#pragma unroll
  for (int i = 0; i < 2; ++i)
#pragma unroll
    for (int nh = 0; nh < 4; ++nh) oacc[i][nh] = zero;

  const size_t kbase = (size_t)b * 256 * 64;
  const size_t vbase = (size_t)b * 64 * 256;

  for (int p = 0; p < 4; ++p) {
    const int p4 = 4 * p;
    const bool any = (mts[1] >= p4);
    // ---- S compute + in-register tile-column stats + exp write ----
    if (any) {
      bf16x8 kf[4][2];
#pragma unroll
      for (int c = 0; c < 4; ++c)
#pragma unroll
        for (int kk = 0; kk < 2; ++kk)
          kf[c][kk] = *(const bf16x8*)(kg + kbase + (size_t)(p * 64 + c * 16 + l15) * 64 + kk * 32 + lhi * 8);
#pragma unroll
      for (int i = 0; i < 2; ++i) {
        const int mt = mts[i];
        if (mt < p4) continue;
        const int cmax = mt - p4;
        const int rowb = mt * 16 + lhi * 4;
#pragma unroll
        for (int c = 0; c < 4; ++c) {
          const int cs = c * 16 + l15;
          if (c <= cmax) {
            f32x4 s = zero;
            s = mfma16(qf[i][0], kf[c][0], s);
            s = mfma16(qf[i][1], kf[c][1], s);
            const int cg = p * 64 + cs;
            const bool v0 = (rowb + 0) >= cg, v1 = (rowb + 1) >= cg;
            const bool v2 = (rowb + 2) >= cg, v3 = (rowb + 3) >= cg;
            float m = -1e30f;
            m = fmaxf(m, v0 ? s[0] : -1e30f);
            m = fmaxf(m, v1 ? s[1] : -1e30f);
            m = fmaxf(m, v2 ? s[2] : -1e30f);
            m = fmaxf(m, v3 ? s[3] : -1e30f);
            m = fmaxf(m, __shfl_xor(m, 16));
            m = fmaxf(m, __shfl_xor(m, 32));
            const float e0 = v0 ? __expf(s[0] - m) : 0.f;
            const float e1 = v1 ? __expf(s[1] - m) : 0.f;
            const float e2 = v2 ? __expf(s[2] - m) : 0.f;
            const float e3 = v3 ? __expf(s[3] - m) : 0.f;
            float t = e0 + e1 + e2 + e3;
            t += __shfl_xor(t, 16);
            t += __shfl_xor(t, 32);
            Sx[rowb + 0][cs] = f2bf(e0);
            Sx[rowb + 1][cs] = f2bf(e1);
            Sx[rowb + 2][cs] = f2bf(e2);
            Sx[rowb + 3][cs] = f2bf(e3);
            if (lhi == 0) { pm[mt * 64 + cs] = m; ps[mt * 64 + cs] = t; }
          } else {
            if (lhi == 0) { pm[mt * 64 + cs] = -1e30f; ps[mt * 64 + cs] = 0.f; }
          }
        }
      }
    }
    __syncthreads();  // B1: pm/ps/Sx stripe complete
    // ---- per-column reduce (redundant across waves; each wave writes its gg rows) ----
    {
      float M = -1e30f;
      for (int mt = p4; mt < 16; ++mt) M = fmaxf(M, pm[mt * 64 + lane]);
      float L = 0.f;
      for (int mt = p4; mt < 16; ++mt) L += ps[mt * 64 + lane] * __expf(pm[mt * 64 + lane] - M);
      const float rv = 1.0f / L;
      int mtw = p4 + w;
      if (mtw < 16) gg[mtw * 64 + lane] = __expf(pm[mtw * 64 + lane] - M) * rv;
      mtw += 8;
      if (mtw < 16) gg[mtw * 64 + lane] = __expf(pm[mtw * 64 + lane] - M) * rv;
    }
    __syncthreads();  // B2: gg ready
    // ---- W = Sx * gg, PV accumulate ----
    if (any) {
      bf16x8 vf[4][2];
#pragma unroll
      for (int nh = 0; nh < 4; ++nh)
#pragma unroll
        for (int kk = 0; kk < 2; ++kk)
          vf[nh][kk] = *(const bf16x8*)(vg + vbase + (size_t)(nh * 16 + l15) * 256 + p * 64 + kk * 32 + lhi * 8);
#pragma unroll
      for (int i = 0; i < 2; ++i) {
        const int mt = mts[i];
        if (mt < p4) continue;
        const int grow = mt * 16 + l15;
        const int dmax = mt - p4;
#pragma unroll
        for (int kk = 0; kk < 2; ++kk) {
          if (kk == 1 && dmax <= 1) continue;  // upper half fully masked
          const int c0 = kk * 32 + lhi * 8;
          bf16x8 se = *(const bf16x8*)&Sx[grow][c0];
          f32x4 gA = *(const f32x4*)&gg[mt * 64 + c0];
          f32x4 gB = *(const f32x4*)&gg[mt * 64 + c0 + 4];
          const int cg0 = p * 64 + c0;
          bf16x8 wfr;
#pragma unroll
          for (int j = 0; j < 4; ++j)
            wfr[j] = (cg0 + j <= grow) ? (__bf16)((float)se[j] * gA[j]) : (__bf16)0.f;
#pragma unroll
          for (int j = 0; j < 4; ++j)
            wfr[4 + j] = (cg0 + 4 + j <= grow) ? (__bf16)((float)se[4 + j] * gB[j]) : (__bf16)0.f;
#pragma unroll
          for (int nh = 0; nh < 4; ++nh) oacc[i][nh] = mfma16(wfr, vf[nh][kk], oacc[i][nh]);
        }
      }
    }
  }
  // ---- output ----
#pragma unroll
  for (int i = 0; i < 2; ++i) {
    const int rb = mts[i] * 16 + lhi * 4;
#pragma unroll
    for (int nh = 0; nh < 4; ++nh) {
      const int h = nh * 16 + l15;
#pragma unroll
      for (int r = 0; r < 4; ++r)
        out[(size_t)b * 16384 + (size_t)(rb + r) * 64 + h] = oacc[i][nh][r];
    }
  }
}

extern "C" void kernel_launch(void* const* d_in, const int* in_sizes, int n_in,
                              void* d_out, int out_size, void* d_ws, size_t ws_size,
                              hipStream_t stream) {
  const float* x  = (const float*)d_in[0];
  const float* Wq = (const float*)d_in[1];
  const float* Wk = (const float*)d_in[2];
  const float* Wv = (const float*)d_in[3];
  float* out = (float*)d_out;

  unsigned short* kg = (unsigned short*)d_ws;              // [512][256][64] bf16
  unsigned short* vg = kg + (size_t)512 * 256 * 64;        // [512][64][256] bf16
  unsigned short* wf = vg + (size_t)512 * 256 * 64;        // 73728 bf16 frag-packed

  repack_w<<<144, 512, 0, stream>>>(Wq, Wk, Wv, wf);
  fused<<<512, 512, 0, stream>>>(x, wf, kg, vg, out);
}

// Round 7
// 91.629 us; speedup vs baseline: 3.1945x; 1.1212x over previous
//
#include <hip/hip_runtime.h>

typedef float  f32x4  __attribute__((ext_vector_type(4)));
typedef __bf16 bf16x8 __attribute__((ext_vector_type(8)));

#define CC 384
#define AS1 __attribute__((address_space(1)))
#define AS3 __attribute__((address_space(3)))

__device__ __forceinline__ unsigned short f2bf(float f) {
  union { float f; unsigned int u; } x; x.f = f;
  unsigned int u = x.u;
  return (unsigned short)((u + 0x7fffu + ((u >> 16) & 1u)) >> 16);
}

__device__ __forceinline__ f32x4 mfma16(bf16x8 a, bf16x8 b, f32x4 c) {
  return __builtin_amdgcn_mfma_f32_16x16x32_bf16(a, b, c, 0, 0, 0);
}

// ---------------- kernel 0: repack W into B-fragment layout ----------------
// dst: [kk(0..11)][nt(0..11)][lane(0..63)][j(0..7)] bf16
// element (k, n): kk=k>>5, lane=((k>>3)&3)*16 + (n&15), j=k&7, nt=n>>4
__global__ void repack_w(const float* __restrict__ Wq, const float* __restrict__ Wk,
                         const float* __restrict__ Wv, unsigned short* __restrict__ wf) {
  int e = blockIdx.x * 512 + threadIdx.x;      // 73728 total, exact
  int k = e / 192;
  int n = e - k * 192;
  const float* W = (n < 64) ? Wq : (n < 128) ? Wk : Wv;
  float val = W[k * 64 + (n & 63)];
  int kk = k >> 5;
  int lane = (((k >> 3) & 3) << 4) | (n & 15);
  int j = k & 7;
  int nt = n >> 4;
  wf[(size_t)(((kk * 12 + nt) << 6) + lane) * 8 + j] = f2bf(val);
}

// ---------------- fused kernel: pipelined projection + column-softmax attention --------
// one block per batch, 8 waves; wave w owns m-tiles {w, 15-w} for BOTH stages.
// Occupancy note (measured R4-R6): acc[2][12] = 96 AGPRs/thread => total regs ~200+,
// so 2 blocks/CU is unreachable; performance comes from counted-vmcnt pipelining
// (prefetch stays in flight ACROSS barriers), not occupancy.
__global__ __launch_bounds__(512, 2) void fused(const float* __restrict__ x,
                                                const unsigned short* __restrict__ wf,
                                                float* __restrict__ out) {
  // LDS layout (119,808 B):
  //  [0, 73728)        projection: wst[3][24576B]  |  attention: Sx[256][72] + kL[256][72]
  //  [73728, 107520)   vT[64][264] bf16
  //  [107520, 119808)  pm/ps/gg [16][64] f32 each
  __shared__ __attribute__((aligned(16))) unsigned char smem[119808];
  unsigned short (*Sx)[72] = (unsigned short(*)[72])smem;
  unsigned short (*kL)[72] = (unsigned short(*)[72])(smem + 36864);
  unsigned short (*vT)[264] = (unsigned short(*)[264])(smem + 73728);
  float* pm = (float*)(smem + 107520);
  float* ps = pm + 1024;
  float* gg = ps + 1024;
  unsigned short* wst = (unsigned short*)smem;   // 3 x 12288 shorts (24KB each)

  const int tid = threadIdx.x;
  const int w = tid >> 6, lane = tid & 63;
  const int l15 = lane & 15, lhi = lane >> 4;
  const int b = blockIdx.x;
  const int mts[2] = {w, 15 - w};

  // ================= projection: 6 phases of K=64, counted-vmcnt pipeline =================
  const float* xr0 = x + ((size_t)b * 256 + mts[0] * 16 + l15) * CC + lhi * 8;
  const float* xr1 = x + ((size_t)b * 256 + mts[1] * 16 + l15) * CC + lhi * 8;

  f32x4 zero = {0.f, 0.f, 0.f, 0.f};
  f32x4 acc[2][12];
#pragma unroll
  for (int i = 0; i < 2; ++i)
#pragma unroll
    for (int nt = 0; nt < 12; ++nt) acc[i][nt] = zero;

  f32x4 xreg[2][8];   // x prefetch double-buffer (64 VGPR)

  // stage phase kp's 24,576-B W chunk into buffer b_ (3 x 16B per thread, lane-linear)
#define WSTAGE(kp_, b_) do {                                                                  \
    const unsigned short* s_ = wf + (size_t)(kp_) * 12288 + tid * 8;                          \
    unsigned short* d_ = wst + (b_) * 12288 + tid * 8;                                        \
    __builtin_amdgcn_global_load_lds((const AS1 void*)(s_),        (AS3 void*)(d_),        16, 0, 0); \
    __builtin_amdgcn_global_load_lds((const AS1 void*)(s_ + 4096), (AS3 void*)(d_ + 4096), 16, 0, 0); \
    __builtin_amdgcn_global_load_lds((const AS1 void*)(s_ + 8192), (AS3 void*)(d_ + 8192), 16, 0, 0); \
  } while (0)
  // load x cols [kp*64, kp*64+64) for both row-groups into xreg[s_] (8 x 16B)
#define XLOAD(kp_, s_) do {                                                                   \
    const int o_ = (kp_) * 64;                                                                \
    xreg[s_][0] = *(const f32x4*)(xr0 + o_);      xreg[s_][1] = *(const f32x4*)(xr0 + o_ + 4);  \
    xreg[s_][2] = *(const f32x4*)(xr0 + o_ + 32); xreg[s_][3] = *(const f32x4*)(xr0 + o_ + 36); \
    xreg[s_][4] = *(const f32x4*)(xr1 + o_);      xreg[s_][5] = *(const f32x4*)(xr1 + o_ + 4);  \
    xreg[s_][6] = *(const f32x4*)(xr1 + o_ + 32); xreg[s_][7] = *(const f32x4*)(xr1 + o_ + 36); \
  } while (0)

  // prologue: S(0), S(1), X(0); wait S(0) done (11 younger: S(1)=3 + X(0)=8)
  WSTAGE(0, 0);
  WSTAGE(1, 1);
  XLOAD(0, 0);
  __builtin_amdgcn_sched_barrier(0);
  asm volatile("s_waitcnt vmcnt(11)" ::: "memory");
  __builtin_amdgcn_s_barrier();
  __builtin_amdgcn_sched_barrier(0);

#pragma unroll
  for (int kp = 0; kp < 6; ++kp) {
    const int cur = kp & 1, nxt = cur ^ 1;
    if (kp < 5) XLOAD(kp + 1, nxt);          // 8 vmem ops
    if (kp < 4) WSTAGE(kp + 2, (kp + 2) % 3); // 3 vmem ops
    __builtin_amdgcn_sched_barrier(0);
    const unsigned short* base = wst + (kp % 3) * 12288;
#pragma unroll
    for (int i = 0; i < 2; ++i) {
#pragma unroll
      for (int k2 = 0; k2 < 2; ++k2) {
        bf16x8 af;
#pragma unroll
        for (int j = 0; j < 4; ++j) {
          af[j]     = (__bf16)xreg[cur][i * 4 + k2 * 2][j];
          af[4 + j] = (__bf16)xreg[cur][i * 4 + k2 * 2 + 1][j];
        }
        const bf16x8* bp = (const bf16x8*)(base + k2 * 6144) + lane;
#pragma unroll
        for (int nt = 0; nt < 12; ++nt) acc[i][nt] = mfma16(af, bp[nt * 64], acc[i][nt]);
      }
    }
    __builtin_amdgcn_sched_barrier(0);
    // ensure S(kp+1) complete before barrier; leave X(kp+1)+S(kp+2) in flight
    if (kp < 4)       asm volatile("s_waitcnt vmcnt(11)" ::: "memory");
    else if (kp == 4) asm volatile("s_waitcnt vmcnt(8)" ::: "memory");
    if (kp < 5) {
      __builtin_amdgcn_s_barrier();
      __builtin_amdgcn_sched_barrier(0);
    }
  }
#undef WSTAGE
#undef XLOAD
  __syncthreads();  // full drain; wst region free for Sx/kL epilogue writes

  // epilogue: q (scaled) -> Sx scratch, k -> kL, v -> vT (transposed, packed b64)
  const float qs = 0.05103103630798288f;  // 384^-0.5
#pragma unroll
  for (int i = 0; i < 2; ++i) {
    const int rb = mts[i] * 16 + lhi * 4;
#pragma unroll
    for (int nt = 0; nt < 4; ++nt) {
      const int h = nt * 16 + l15;
#pragma unroll
      for (int r = 0; r < 4; ++r) Sx[rb + r][h] = f2bf(acc[i][nt][r] * qs);
    }
#pragma unroll
    for (int nt = 4; nt < 8; ++nt) {
      const int h = (nt - 4) * 16 + l15;
#pragma unroll
      for (int r = 0; r < 4; ++r) kL[rb + r][h] = f2bf(acc[i][nt][r]);
    }
#pragma unroll
    for (int nt = 8; nt < 12; ++nt) {
      const int h = (nt - 8) * 16 + l15;
      unsigned long long pk =
          (unsigned long long)f2bf(acc[i][nt][0]) |
          ((unsigned long long)f2bf(acc[i][nt][1]) << 16) |
          ((unsigned long long)f2bf(acc[i][nt][2]) << 32) |
          ((unsigned long long)f2bf(acc[i][nt][3]) << 48);
      *(unsigned long long*)&vT[h][rb] = pk;
    }
  }
  __syncthreads();  // q/k/v LDS-resident

  bf16x8 qf[2][2];
#pragma unroll
  for (int i = 0; i < 2; ++i)
#pragma unroll
    for (int kk = 0; kk < 2; ++kk)
      qf[i][kk] = *(const bf16x8*)&Sx[mts[i] * 16 + l15][kk * 32 + lhi * 8];

  // ================= attention =================
  f32x4 oacc[2][4];
#pragma unroll
  for (int i = 0; i < 2; ++i)
#pragma unroll
    for (int nh = 0; nh < 4; ++nh) oacc[i][nh] = zero;

  for (int p = 0; p < 4; ++p) {
    const int p4 = 4 * p;
    const bool any = (mts[1] >= p4);
    // ---- S compute + in-register tile-column stats + exp write ----
    if (any) {
      bf16x8 kf[4][2];
#pragma unroll
      for (int c = 0; c < 4; ++c)
#pragma unroll
        for (int kk = 0; kk < 2; ++kk)
          kf[c][kk] = *(const bf16x8*)&kL[p * 64 + c * 16 + l15][kk * 32 + lhi * 8];
#pragma unroll
      for (int i = 0; i < 2; ++i) {
        const int mt = mts[i];
        if (mt < p4) continue;
        const int cmax = mt - p4;
        const int rowb = mt * 16 + lhi * 4;
#pragma unroll
        for (int c = 0; c < 4; ++c) {
          const int cs = c * 16 + l15;
          if (c <= cmax) {
            f32x4 s = zero;
            s = mfma16(qf[i][0], kf[c][0], s);
            s = mfma16(qf[i][1], kf[c][1], s);
            const int cg = p * 64 + cs;
            const bool v0 = (rowb + 0) >= cg, v1 = (rowb + 1) >= cg;
            const bool v2 = (rowb + 2) >= cg, v3 = (rowb + 3) >= cg;
            float m = -1e30f;
            m = fmaxf(m, v0 ? s[0] : -1e30f);
            m = fmaxf(m, v1 ? s[1] : -1e30f);
            m = fmaxf(m, v2 ? s[2] : -1e30f);
            m = fmaxf(m, v3 ? s[3] : -1e30f);
            m = fmaxf(m, __shfl_xor(m, 16));
            m = fmaxf(m, __shfl_xor(m, 32));
            const float e0 = v0 ? __expf(s[0] - m) : 0.f;
            const float e1 = v1 ? __expf(s[1] - m) : 0.f;
            const float e2 = v2 ? __expf(s[2] - m) : 0.f;
            const float e3 = v3 ? __expf(s[3] - m) : 0.f;
            float t = e0 + e1 + e2 + e3;
            t += __shfl_xor(t, 16);
            t += __shfl_xor(t, 32);
            Sx[rowb + 0][cs] = f2bf(e0);
            Sx[rowb + 1][cs] = f2bf(e1);
            Sx[rowb + 2][cs] = f2bf(e2);
            Sx[rowb + 3][cs] = f2bf(e3);
            if (lhi == 0) { pm[mt * 64 + cs] = m; ps[mt * 64 + cs] = t; }
          } else {
            if (lhi == 0) { pm[mt * 64 + cs] = -1e30f; ps[mt * 64 + cs] = 0.f; }
          }
        }
      }
    }
    __syncthreads();  // B1: pm/ps/Sx stripe complete
    // ---- per-column reduce (redundant across waves; each wave writes its gg rows) ----
    {
      float M = -1e30f;
      for (int mt = p4; mt < 16; ++mt) M = fmaxf(M, pm[mt * 64 + lane]);
      float L = 0.f;
      for (int mt = p4; mt < 16; ++mt) L += ps[mt * 64 + lane] * __expf(pm[mt * 64 + lane] - M);
      const float rv = 1.0f / L;
      int mtw = p4 + w;
      if (mtw < 16) gg[mtw * 64 + lane] = __expf(pm[mtw * 64 + lane] - M) * rv;
      mtw += 8;
      if (mtw < 16) gg[mtw * 64 + lane] = __expf(pm[mtw * 64 + lane] - M) * rv;
    }
    __syncthreads();  // B2: gg ready
    // ---- W = Sx * gg, PV accumulate ----
    if (any) {
      bf16x8 vf[4][2];
#pragma unroll
      for (int nh = 0; nh < 4; ++nh)
#pragma unroll
        for (int kk = 0; kk < 2; ++kk)
          vf[nh][kk] = *(const bf16x8*)&vT[nh * 16 + l15][p * 64 + kk * 32 + lhi * 8];
#pragma unroll
      for (int i = 0; i < 2; ++i) {
        const int mt = mts[i];
        if (mt < p4) continue;
        const int grow = mt * 16 + l15;
        const int dmax = mt - p4;
#pragma unroll
        for (int kk = 0; kk < 2; ++kk) {
          if (kk == 1 && dmax <= 1) continue;  // upper half fully masked
          const int c0 = kk * 32 + lhi * 8;
          bf16x8 se = *(const bf16x8*)&Sx[grow][c0];
          f32x4 gA = *(const f32x4*)&gg[mt * 64 + c0];
          f32x4 gB = *(const f32x4*)&gg[mt * 64 + c0 + 4];
          const int cg0 = p * 64 + c0;
          bf16x8 wfr;
#pragma unroll
          for (int j = 0; j < 4; ++j)
            wfr[j] = (cg0 + j <= grow) ? (__bf16)((float)se[j] * gA[j]) : (__bf16)0.f;
#pragma unroll
          for (int j = 0; j < 4; ++j)
            wfr[4 + j] = (cg0 + 4 + j <= grow) ? (__bf16)((float)se[4 + j] * gB[j]) : (__bf16)0.f;
#pragma unroll
          for (int nh = 0; nh < 4; ++nh) oacc[i][nh] = mfma16(wfr, vf[nh][kk], oacc[i][nh]);
        }
      }
    }
  }
  // ---- output ----
#pragma unroll
  for (int i = 0; i < 2; ++i) {
    const int rb = mts[i] * 16 + lhi * 4;
#pragma unroll
    for (int nh = 0; nh < 4; ++nh) {
      const int h = nh * 16 + l15;
#pragma unroll
      for (int r = 0; r < 4; ++r)
        out[(size_t)b * 16384 + (size_t)(rb + r) * 64 + h] = oacc[i][nh][r];
    }
  }
}

extern "C" void kernel_launch(void* const* d_in, const int* in_sizes, int n_in,
                              void* d_out, int out_size, void* d_ws, size_t ws_size,
                              hipStream_t stream) {
  const float* x  = (const float*)d_in[0];
  const float* Wq = (const float*)d_in[1];
  const float* Wk = (const float*)d_in[2];
  const float* Wv = (const float*)d_in[3];
  float* out = (float*)d_out;

  unsigned short* wf = (unsigned short*)d_ws;   // 73728 bf16 frag-packed W

  repack_w<<<144, 512, 0, stream>>>(Wq, Wk, Wv, wf);
  fused<<<512, 512, 0, stream>>>(x, wf, out);
}

// Round 8
// 86.582 us; speedup vs baseline: 3.3807x; 1.0583x over previous
//
#include <hip/hip_runtime.h>

typedef float  f32x4  __attribute__((ext_vector_type(4)));
typedef __bf16 bf16x8 __attribute__((ext_vector_type(8)));

#define CC 384
#define AS1 __attribute__((address_space(1)))
#define AS3 __attribute__((address_space(3)))

__device__ __forceinline__ unsigned short f2bf(float f) {
  union { float f; unsigned int u; } x; x.f = f;
  unsigned int u = x.u;
  return (unsigned short)((u + 0x7fffu + ((u >> 16) & 1u)) >> 16);
}

__device__ __forceinline__ f32x4 mfma16(bf16x8 a, bf16x8 b, f32x4 c) {
  return __builtin_amdgcn_mfma_f32_16x16x32_bf16(a, b, c, 0, 0, 0);
}

// ---------------- kernel 0: repack W into B-fragment layout ----------------
// dst: [ks(0..11)][nt(0..11)][lane(0..63)][j(0..7)] bf16
// element (k, n): ks=k>>5, lane=((k>>3)&3)*16 + (n&15), j=k&7, nt=n>>4
__global__ void repack_w(const float* __restrict__ Wq, const float* __restrict__ Wk,
                         const float* __restrict__ Wv, unsigned short* __restrict__ wf) {
  int e = blockIdx.x * 512 + threadIdx.x;      // 73728 total, exact
  int k = e / 192;
  int n = e - k * 192;
  const float* W = (n < 64) ? Wq : (n < 128) ? Wk : Wv;
  float val = W[k * 64 + (n & 63)];
  int kk = k >> 5;
  int lane = (((k >> 3) & 3) << 4) | (n & 15);
  int j = k & 7;
  int nt = n >> 4;
  wf[(size_t)(((kk * 12 + nt) << 6) + lane) * 8 + j] = f2bf(val);
}

// ---------------- fused kernel: projection + column-softmax attention ----------------
// ONE block per batch, 1024 threads / 16 waves (the R8 restructure):
//  - projection: wave w owns m-tile w (16 rows) -> acc[12] = 48 regs/thread
//    (was acc[2][12]=96 with 8 waves; ~200 regs/wave capped residency at 2 waves/SIMD
//     and made the whole kernel latency-bound at <20%% on every pipe, R3-R7 measured)
//  - attention: wave pair {u, u+8} (u=w&7) splits tile-pair {u,15-u}:
//    S-phase by column-half (c 0-1 vs 2-3), PV by head-half (nh 0-1 vs 2-3).
__global__ __launch_bounds__(1024, 4) void fused(const float* __restrict__ x,
                                                 const unsigned short* __restrict__ wf,
                                                 float* __restrict__ out) {
  // LDS layout (119,808 B):
  //  [0, 73728)        attn: Sx[256][72] + kL[256][72]  |  projection: wst 2 x 24,576 B
  //  [73728, 107520)   vT[64][264] bf16
  //  [107520, 119808)  pm/ps/gg [16][64] f32 each
  __shared__ __attribute__((aligned(16))) unsigned char smem[119808];
  unsigned short (*Sx)[72] = (unsigned short(*)[72])smem;
  unsigned short (*kL)[72] = (unsigned short(*)[72])(smem + 36864);
  unsigned short (*vT)[264] = (unsigned short(*)[264])(smem + 73728);
  float* pm = (float*)(smem + 107520);
  float* ps = pm + 1024;
  float* gg = ps + 1024;
  unsigned short* wst = (unsigned short*)smem;   // 2 x 12288 shorts (24,576 B each)

  const int tid = threadIdx.x;
  const int w = tid >> 6, lane = tid & 63;
  const int l15 = lane & 15, lhi = lane >> 4;
  const int b = blockIdx.x;
  const int u = w & 7, chalf = w >> 3;
  const int mts[2] = {u, 15 - u};

  // ================= projection: 6 phases of K=64, 2-buffer LDS W-stage =================
  const float* xr = x + ((size_t)b * 256 + w * 16 + l15) * CC + lhi * 8;

  f32x4 zero = {0.f, 0.f, 0.f, 0.f};
  f32x4 acc[12];
#pragma unroll
  for (int nt = 0; nt < 12; ++nt) acc[nt] = zero;

  // stage phase kp's 24,576-B W chunk (K=64) into buffer b_
#define WSTAGE(kp_, b_) do {                                                                  \
    const unsigned short* s_ = wf + (size_t)(kp_) * 12288 + tid * 8;                          \
    unsigned short* d_ = wst + (b_) * 12288 + tid * 8;                                        \
    __builtin_amdgcn_global_load_lds((const AS1 void*)(s_), (AS3 void*)(d_), 16, 0, 0);       \
    if (tid < 512)                                                                            \
      __builtin_amdgcn_global_load_lds((const AS1 void*)(s_ + 8192), (AS3 void*)(d_ + 8192),  \
                                       16, 0, 0);                                             \
  } while (0)
#define XLOAD(kp_, a_) do {                                                                   \
    const int o_ = (kp_) * 64;                                                                \
    a_[0][0] = *(const f32x4*)(xr + o_);      a_[0][1] = *(const f32x4*)(xr + o_ + 4);        \
    a_[1][0] = *(const f32x4*)(xr + o_ + 32); a_[1][1] = *(const f32x4*)(xr + o_ + 36);       \
  } while (0)

  WSTAGE(0, 0);
  f32x4 aC[2][2];
  XLOAD(0, aC);

  for (int kp = 0; kp < 6; ++kp) {
    __syncthreads();  // buf[kp&1] staged; prev-buf readers done
    f32x4 aN[2][2];
#pragma unroll
    for (int k2 = 0; k2 < 2; ++k2) { aN[k2][0] = zero; aN[k2][1] = zero; }
    if (kp < 5) {
      XLOAD(kp + 1, aN);
      WSTAGE(kp + 1, (kp + 1) & 1);
    }
#pragma unroll
    for (int k2 = 0; k2 < 2; ++k2) {
      bf16x8 af;
#pragma unroll
      for (int j = 0; j < 4; ++j) { af[j] = (__bf16)aC[k2][0][j]; af[4 + j] = (__bf16)aC[k2][1][j]; }
      const bf16x8* bp = (const bf16x8*)(wst + (kp & 1) * 12288 + k2 * 6144) + lane;
#pragma unroll
      for (int nt = 0; nt < 12; ++nt) acc[nt] = mfma16(af, bp[nt * 64], acc[nt]);
    }
#pragma unroll
    for (int k2 = 0; k2 < 2; ++k2) { aC[k2][0] = aN[k2][0]; aC[k2][1] = aN[k2][1]; }
  }
#undef WSTAGE
#undef XLOAD
  __syncthreads();  // all W-stage reads done; Sx/kL regions free

  // epilogue: q (scaled) -> Sx scratch, k -> kL, v -> vT (transposed, packed b64)
  const float qs = 0.05103103630798288f;  // 384^-0.5
  {
    const int rb = w * 16 + lhi * 4;
#pragma unroll
    for (int nt = 0; nt < 4; ++nt) {
      const int h = nt * 16 + l15;
#pragma unroll
      for (int r = 0; r < 4; ++r) Sx[rb + r][h] = f2bf(acc[nt][r] * qs);
    }
#pragma unroll
    for (int nt = 4; nt < 8; ++nt) {
      const int h = (nt - 4) * 16 + l15;
#pragma unroll
      for (int r = 0; r < 4; ++r) kL[rb + r][h] = f2bf(acc[nt][r]);
    }
#pragma unroll
    for (int nt = 8; nt < 12; ++nt) {
      const int h = (nt - 8) * 16 + l15;
      unsigned long long pk =
          (unsigned long long)f2bf(acc[nt][0]) |
          ((unsigned long long)f2bf(acc[nt][1]) << 16) |
          ((unsigned long long)f2bf(acc[nt][2]) << 32) |
          ((unsigned long long)f2bf(acc[nt][3]) << 48);
      *(unsigned long long*)&vT[h][rb] = pk;
    }
  }
  __syncthreads();  // q/k/v LDS-resident

  bf16x8 qf[2][2];
#pragma unroll
  for (int i = 0; i < 2; ++i)
#pragma unroll
    for (int kk = 0; kk < 2; ++kk)
      qf[i][kk] = *(const bf16x8*)&Sx[mts[i] * 16 + l15][kk * 32 + lhi * 8];
  __syncthreads();  // B0: qf loaded before any wave overwrites Sx (cross-wave rows now)

  // ================= attention =================
  f32x4 oacc[2][2];   // [tile][nh-half]; this wave owns head cols chalf*32 .. +31
#pragma unroll
  for (int i = 0; i < 2; ++i)
#pragma unroll
    for (int nh2 = 0; nh2 < 2; ++nh2) oacc[i][nh2] = zero;

  for (int p = 0; p < 4; ++p) {
    const int p4 = 4 * p;
    const bool any = (mts[1] >= p4);
    // ---- S compute (this wave's column-half) + tile-column stats + exp write ----
    if (any) {
      bf16x8 kf[2][2];
#pragma unroll
      for (int c2 = 0; c2 < 2; ++c2) {
        const int c = chalf * 2 + c2;
#pragma unroll
        for (int kk = 0; kk < 2; ++kk)
          kf[c2][kk] = *(const bf16x8*)&kL[p * 64 + c * 16 + l15][kk * 32 + lhi * 8];
      }
#pragma unroll
      for (int i = 0; i < 2; ++i) {
        const int mt = mts[i];
        if (mt < p4) continue;
        const int cmax = mt - p4;
        const int rowb = mt * 16 + lhi * 4;
#pragma unroll
        for (int c2 = 0; c2 < 2; ++c2) {
          const int c = chalf * 2 + c2;
          const int cs = c * 16 + l15;
          if (c <= cmax) {
            f32x4 s = zero;
            s = mfma16(qf[i][0], kf[c2][0], s);
            s = mfma16(qf[i][1], kf[c2][1], s);
            const int cg = p * 64 + cs;
            const bool v0 = (rowb + 0) >= cg, v1 = (rowb + 1) >= cg;
            const bool v2 = (rowb + 2) >= cg, v3 = (rowb + 3) >= cg;
            float m = -1e30f;
            m = fmaxf(m, v0 ? s[0] : -1e30f);
            m = fmaxf(m, v1 ? s[1] : -1e30f);
            m = fmaxf(m, v2 ? s[2] : -1e30f);
            m = fmaxf(m, v3 ? s[3] : -1e30f);
            m = fmaxf(m, __shfl_xor(m, 16));
            m = fmaxf(m, __shfl_xor(m, 32));
            const float e0 = v0 ? __expf(s[0] - m) : 0.f;
            const float e1 = v1 ? __expf(s[1] - m) : 0.f;
            const float e2 = v2 ? __expf(s[2] - m) : 0.f;
            const float e3 = v3 ? __expf(s[3] - m) : 0.f;
            float t = e0 + e1 + e2 + e3;
            t += __shfl_xor(t, 16);
            t += __shfl_xor(t, 32);
            Sx[rowb + 0][cs] = f2bf(e0);
            Sx[rowb + 1][cs] = f2bf(e1);
            Sx[rowb + 2][cs] = f2bf(e2);
            Sx[rowb + 3][cs] = f2bf(e3);
            if (lhi == 0) { pm[mt * 64 + cs] = m; ps[mt * 64 + cs] = t; }
          } else {
            if (lhi == 0) { pm[mt * 64 + cs] = -1e30f; ps[mt * 64 + cs] = 0.f; }
          }
        }
      }
    }
    __syncthreads();  // B1: pm/ps/Sx stripe complete
    // ---- per-column reduce (redundant across waves; wave w writes gg row p4+w) ----
    {
      float M = -1e30f;
      for (int mt = p4; mt < 16; ++mt) M = fmaxf(M, pm[mt * 64 + lane]);
      float L = 0.f;
      for (int mt = p4; mt < 16; ++mt) L += ps[mt * 64 + lane] * __expf(pm[mt * 64 + lane] - M);
      const float rv = 1.0f / L;
      const int mtw = p4 + w;
      if (mtw < 16) gg[mtw * 64 + lane] = __expf(pm[mtw * 64 + lane] - M) * rv;
    }
    __syncthreads();  // B2: gg ready
    // ---- W = Sx * gg, PV accumulate (this wave's head-half) ----
    if (any) {
      bf16x8 vf[2][2];
#pragma unroll
      for (int nh2 = 0; nh2 < 2; ++nh2)
#pragma unroll
        for (int kk = 0; kk < 2; ++kk)
          vf[nh2][kk] = *(const bf16x8*)&vT[(chalf * 2 + nh2) * 16 + l15][p * 64 + kk * 32 + lhi * 8];
#pragma unroll
      for (int i = 0; i < 2; ++i) {
        const int mt = mts[i];
        if (mt < p4) continue;
        const int grow = mt * 16 + l15;
        const int dmax = mt - p4;
#pragma unroll
        for (int kk = 0; kk < 2; ++kk) {
          if (kk == 1 && dmax <= 1) continue;  // upper half fully masked
          const int c0 = kk * 32 + lhi * 8;
          bf16x8 se = *(const bf16x8*)&Sx[grow][c0];
          f32x4 gA = *(const f32x4*)&gg[mt * 64 + c0];
          f32x4 gB = *(const f32x4*)&gg[mt * 64 + c0 + 4];
          const int cg0 = p * 64 + c0;
          bf16x8 wfr;
#pragma unroll
          for (int j = 0; j < 4; ++j)
            wfr[j] = (cg0 + j <= grow) ? (__bf16)((float)se[j] * gA[j]) : (__bf16)0.f;
#pragma unroll
          for (int j = 0; j < 4; ++j)
            wfr[4 + j] = (cg0 + 4 + j <= grow) ? (__bf16)((float)se[4 + j] * gB[j]) : (__bf16)0.f;
#pragma unroll
          for (int nh2 = 0; nh2 < 2; ++nh2) oacc[i][nh2] = mfma16(wfr, vf[nh2][kk], oacc[i][nh2]);
        }
      }
    }
    __syncthreads();  // B3: PV readers done before next phase's Sx writes (cross-wave rows)
  }
  // ---- output: this wave's head-half columns of its tile-pair rows ----
#pragma unroll
  for (int i = 0; i < 2; ++i) {
    const int rb = mts[i] * 16 + lhi * 4;
#pragma unroll
    for (int nh2 = 0; nh2 < 2; ++nh2) {
      const int h = (chalf * 2 + nh2) * 16 + l15;
#pragma unroll
      for (int r = 0; r < 4; ++r)
        out[(size_t)b * 16384 + (size_t)(rb + r) * 64 + h] = oacc[i][nh2][r];
    }
  }
}

extern "C" void kernel_launch(void* const* d_in, const int* in_sizes, int n_in,
                              void* d_out, int out_size, void* d_ws, size_t ws_size,
                              hipStream_t stream) {
  const float* x  = (const float*)d_in[0];
  const float* Wq = (const float*)d_in[1];
  const float* Wk = (const float*)d_in[2];
  const float* Wv = (const float*)d_in[3];
  float* out = (float*)d_out;

  unsigned short* wf = (unsigned short*)d_ws;   // 73728 bf16 frag-packed W

  repack_w<<<144, 512, 0, stream>>>(Wq, Wk, Wv, wf);
  fused<<<512, 1024, 0, stream>>>(x, wf, out);
}